// Round 10
// baseline (359.922 us; speedup 1.0000x reference)
//
#include <hip/hip_runtime.h>
#include <stdint.h>

typedef __bf16 bf16;
typedef __bf16 bf16x8 __attribute__((ext_vector_type(8)));
typedef __bf16 bf16x4 __attribute__((ext_vector_type(4)));
typedef float  f32x4  __attribute__((ext_vector_type(4)));
typedef uint32_t u32;

#define BATCH    65536
#define NCAT     640      // 599 spline logits + a + b, padded to 640
#define SPSTRIDE 608      // sp row stride: 1216 B = 19 x 64 B (sector-aligned rows)

#define MFMA __builtin_amdgcn_mfma_f32_16x16x32_bf16
#define FENCE() asm volatile("" ::: "memory")

// async global->LDS, 16B per lane; LDS dest = wave-uniform base + lane*16
__device__ __forceinline__ void async16(const void* g, void* l) {
    __builtin_amdgcn_global_load_lds(
        (const u32 __attribute__((address_space(1)))*)g,
        (u32 __attribute__((address_space(3)))*)l,
        16, 0, 0);
}

// ---------------------------------------------------------------------------
// Kernel 0: weights -> bf16; Wcat[640][512] = [WV; Wa; Wb; 0]; inputs -> bf16
// ---------------------------------------------------------------------------
__global__ __launch_bounds__(256) void prep_kernel(
    const float* W1, const float* W2, const float* WV,
    const float* bV, const float* Wa, const float* ba,
    const float* Wb, const float* bb, const float* inputs,
    bf16* w1b, bf16* w2b, bf16* wcat, float* bcat, bf16* xin)
{
    int idx = blockIdx.x * 256 + threadIdx.x;
    const int n1 = 512 * 128, n2 = 512 * 512, n3 = NCAT * 512;
    const int n5 = BATCH * 128 / 8;                 // 8 floats per item
    if (idx < n5) {                                  // input cast (bulk) first
        const float4* src = (const float4*)(inputs + idx * 8);
        float4 v0 = src[0], v1 = src[1];
        bf16x8 h;
        h[0]=(bf16)v0.x; h[1]=(bf16)v0.y; h[2]=(bf16)v0.z; h[3]=(bf16)v0.w;
        h[4]=(bf16)v1.x; h[5]=(bf16)v1.y; h[6]=(bf16)v1.z; h[7]=(bf16)v1.w;
        *(bf16x8*)&xin[idx * 8] = h;
        return;
    }
    idx -= n5;
    if (idx < n1) { w1b[idx] = (bf16)W1[idx]; return; }
    idx -= n1;
    if (idx < n2) { w2b[idx] = (bf16)W2[idx]; return; }
    idx -= n2;
    if (idx < n3) {
        int n = idx >> 9, k = idx & 511;
        float v = 0.f;
        if (n < 599)       v = WV[n * 512 + k];
        else if (n == 599) v = Wa[k];
        else if (n == 600) v = Wb[k];
        wcat[idx] = (bf16)v;
        return;
    }
    idx -= n3;
    if (idx < NCAT) {
        float v = 0.f;
        if (idx < 599)       v = bV[idx];
        else if (idx == 599) v = ba[0];
        else if (idx == 600) v = bb[0];
        bcat[idx] = v;
    }
}

// ---------------------------------------------------------------------------
// G1/G2: C[128 x 512] = A[128 x K] @ W[512 x K]^T + b -> LN -> ReLU -> bf16
// 16 waves 2Mx8N, wave tile 64x64 (acc[4][4]) -> B-frag LDS redundancy 2
// (was 4 with 4Mx4N). B: dbuf LDS via global_load_lds. A: direct->VGPR,
// depth-1 prefetch. Counted vmcnt(4) + raw s_barrier per K-step.
// Output staged in LDS (two 64-row halves) -> dense 16B stores.
// ---------------------------------------------------------------------------
template <int KDIM>
__global__ __launch_bounds__(1024, 4) void gemm_ln(
    const bf16* __restrict__ A, const bf16* __restrict__ W,
    const float* __restrict__ bias, const float* __restrict__ gamma,
    const float* __restrict__ beta, bf16* out)
{
    __shared__ __align__(16) char smem[65536];      // B dbuf 2x32K; stage-out
    __shared__ float Psum[128][8], Psq[128][8];

    const int t = threadIdx.x;
    const int lane = t & 63, wid = t >> 6;
    const int wm = wid >> 3, wn = wid & 7;          // 2M x 8N
    const int l16 = lane & 15, g16 = lane >> 4;
    const long row0 = (long)blockIdx.x * 128;
    constexpr int NT = KDIM / 32;

    const bf16* arow = A + (row0 + wm * 64 + l16) * (long)KDIM + g16 * 8;

    f32x4 acc[4][4];
#pragma unroll
    for (int a = 0; a < 4; ++a)
#pragma unroll
        for (int b = 0; b < 4; ++b) acc[a][b] = (f32x4){0.f, 0.f, 0.f, 0.f};

    auto stageB = [&](int kt, int bi) {     // 32 calls of 1KB: 2 per wave
#pragma unroll
        for (int c = 0; c < 2; ++c) {
            int call = c * 16 + wid;
            int row = call * 16 + (lane >> 2);
            const bf16* src = W + (long)row * KDIM + kt * 32 + (lane & 3) * 8;
            async16(src, smem + bi * 32768 + call * 1024);
        }
    };

    bf16x8 af[4];
    stageB(0, 0);
    FENCE();
#pragma unroll
    for (int fm = 0; fm < 4; ++fm) af[fm] = *(const bf16x8*)(arow + fm * 16 * KDIM);
    asm volatile("s_waitcnt vmcnt(4)\n\ts_barrier" ::: "memory");

    for (int kt = 0; kt < NT; ++kt) {
        const int bi = kt & 1;
        bf16x8 a0 = af[0], a1 = af[1], a2 = af[2], a3 = af[3];
        if (kt + 1 < NT) {
            stageB(kt + 1, bi ^ 1);
            FENCE();
            const bf16* ap = arow + (kt + 1) * 32;
#pragma unroll
            for (int fm = 0; fm < 4; ++fm) af[fm] = *(const bf16x8*)(ap + fm * 16 * KDIM);
        }
        const bf16* Bb = (const bf16*)(smem + bi * 32768);
        __builtin_amdgcn_s_setprio(1);
#pragma unroll
        for (int fn = 0; fn < 4; ++fn) {
            bf16x8 bv = *(const bf16x8*)(Bb + (wn * 64 + fn * 16 + l16) * 32 + g16 * 8);
            acc[0][fn] = MFMA(a0, bv, acc[0][fn], 0, 0, 0);
            acc[1][fn] = MFMA(a1, bv, acc[1][fn], 0, 0, 0);
            acc[2][fn] = MFMA(a2, bv, acc[2][fn], 0, 0, 0);
            acc[3][fn] = MFMA(a3, bv, acc[3][fn], 0, 0, 0);
        }
        __builtin_amdgcn_s_setprio(0);
        if (kt + 1 < NT)
            asm volatile("s_waitcnt vmcnt(4)\n\ts_barrier" ::: "memory");
    }

    // ---- epilogue: +bias, LN over 512, ReLU -> two-half staged writeout ----
    float gv[4], bev[4];
#pragma unroll
    for (int fn = 0; fn < 4; ++fn) {
        int col = wn * 64 + fn * 16 + l16;
        float bv = bias[col];
        gv[fn] = gamma[col]; bev[fn] = beta[col];
#pragma unroll
        for (int fm = 0; fm < 4; ++fm)
#pragma unroll
            for (int i = 0; i < 4; ++i) acc[fm][fn][i] += bv;
    }
#pragma unroll
    for (int fm = 0; fm < 4; ++fm)
#pragma unroll
        for (int i = 0; i < 4; ++i) {
            float s = 0.f, q = 0.f;
#pragma unroll
            for (int fn = 0; fn < 4; ++fn) { float v = acc[fm][fn][i]; s += v; q += v * v; }
#pragma unroll
            for (int m = 1; m < 16; m <<= 1) { s += __shfl_xor(s, m); q += __shfl_xor(q, m); }
            if (l16 == 0) {
                int lr = wm * 64 + fm * 16 + g16 * 4 + i;
                Psum[lr][wn] = s; Psq[lr][wn] = q;
            }
        }
    __syncthreads();
    float mmean[4][4], mrstd[4][4];
#pragma unroll
    for (int fm = 0; fm < 4; ++fm)
#pragma unroll
        for (int i = 0; i < 4; ++i) {
            int lr = wm * 64 + fm * 16 + g16 * 4 + i;
            float s = 0.f, q = 0.f;
#pragma unroll
            for (int g = 0; g < 8; ++g) { s += Psum[lr][g]; q += Psq[lr][g]; }
            float mean = s * (1.f / 512.f);
            float var  = q * (1.f / 512.f) - mean * mean;
            mmean[fm][i] = mean;
            mrstd[fm][i] = rsqrtf(var + 1e-5f);
        }
    bf16* stg = (bf16*)smem;
#pragma unroll
    for (int h = 0; h < 2; ++h) {
        __syncthreads();
        if (wm == h) {
#pragma unroll
            for (int fm = 0; fm < 4; ++fm)
#pragma unroll
                for (int i = 0; i < 4; ++i) {
                    int lr = fm * 16 + g16 * 4 + i;      // row within half
#pragma unroll
                    for (int fn = 0; fn < 4; ++fn) {
                        int col = wn * 64 + fn * 16 + l16;
                        float o = (acc[fm][fn][i] - mmean[fm][i]) * mrstd[fm][i] * gv[fn] + bev[fn];
                        stg[lr * 512 + col] = (bf16)fmaxf(o, 0.f);
                    }
                }
        }
        __syncthreads();
#pragma unroll
        for (int it = 0; it < 4; ++it) {          // 64 rows x 1KB dense
            int idx = it * 1024 + t;
            *(bf16x8*)&out[(row0 + h * 64 + (idx >> 6)) * 512 + (idx & 63) * 8] =
                *(const bf16x8*)&stg[idx * 8];
        }
    }
}

// ---------------------------------------------------------------------------
// G3: sp[128 x 640] = X2[128 x 512] @ Wcat^T + bcat.
// 16 waves 2Mx8N, wave tile 64x80 (acc[4][5]); B dbuf + global_load_lds;
// A direct depth-1 prefetch; counted vmcnt(4) + raw barrier.
// Two-half staged dense sp writeout (stride 608 -> 64B-aligned rows).
// ---------------------------------------------------------------------------
__global__ __launch_bounds__(1024, 4) void gemm_cat(
    const bf16* __restrict__ A, const bf16* __restrict__ W,
    const float* __restrict__ bcat, bf16* __restrict__ sp, float* __restrict__ ab)
{
    __shared__ __align__(16) char smem[81920];      // B dbuf 2x40K; stage-out

    const int t = threadIdx.x;
    const int lane = t & 63, wid = t >> 6;
    const int wm = wid >> 3, wn = wid & 7;          // 2M x 8N
    const int l16 = lane & 15, g16 = lane >> 4;
    const long row0 = (long)blockIdx.x * 128;

    const bf16* arow = A + (row0 + wm * 64 + l16) * 512 + g16 * 8;

    f32x4 acc[4][5];
#pragma unroll
    for (int a = 0; a < 4; ++a)
#pragma unroll
        for (int b = 0; b < 5; ++b) acc[a][b] = (f32x4){0.f, 0.f, 0.f, 0.f};

    auto stageB = [&](int kt, int bi) {     // 40 calls of 1KB
#pragma unroll
        for (int c = 0; c < 3; ++c) {
            int call = c * 16 + wid;
            if (call < 40) {
                int row = call * 16 + (lane >> 2);
                const bf16* src = W + (long)row * 512 + kt * 32 + (lane & 3) * 8;
                async16(src, smem + bi * 40960 + call * 1024);
            }
        }
    };

    bf16x8 af[4];
    stageB(0, 0);
    FENCE();
#pragma unroll
    for (int fm = 0; fm < 4; ++fm) af[fm] = *(const bf16x8*)(arow + fm * 16 * 512);
    asm volatile("s_waitcnt vmcnt(4)\n\ts_barrier" ::: "memory");

    for (int kt = 0; kt < 16; ++kt) {
        const int bi = kt & 1;
        bf16x8 a0 = af[0], a1 = af[1], a2 = af[2], a3 = af[3];
        if (kt + 1 < 16) {
            stageB(kt + 1, bi ^ 1);
            FENCE();
            const bf16* ap = arow + (kt + 1) * 32;
#pragma unroll
            for (int fm = 0; fm < 4; ++fm) af[fm] = *(const bf16x8*)(ap + fm * 16 * 512);
        }
        const bf16* Bb = (const bf16*)(smem + bi * 40960);
        __builtin_amdgcn_s_setprio(1);
#pragma unroll
        for (int fn = 0; fn < 5; ++fn) {
            bf16x8 bv = *(const bf16x8*)(Bb + (wn * 80 + fn * 16 + l16) * 32 + g16 * 8);
            acc[0][fn] = MFMA(a0, bv, acc[0][fn], 0, 0, 0);
            acc[1][fn] = MFMA(a1, bv, acc[1][fn], 0, 0, 0);
            acc[2][fn] = MFMA(a2, bv, acc[2][fn], 0, 0, 0);
            acc[3][fn] = MFMA(a3, bv, acc[3][fn], 0, 0, 0);
        }
        __builtin_amdgcn_s_setprio(0);
        if (kt + 1 < 16)
            asm volatile("s_waitcnt vmcnt(4)\n\ts_barrier" ::: "memory");
    }
    __syncthreads();                        // drain; B bufs dead

    // ---- +bcat; ab f32 direct; two-half staged dense writeout ----
    float bv[5];
#pragma unroll
    for (int fn = 0; fn < 5; ++fn) bv[fn] = bcat[wn * 80 + fn * 16 + l16];

#pragma unroll
    for (int fn = 0; fn < 5; ++fn) {
        int col = wn * 80 + fn * 16 + l16;
        if (col == 599 || col == 600) {
#pragma unroll
            for (int fm = 0; fm < 4; ++fm)
#pragma unroll
                for (int i = 0; i < 4; ++i) {
                    int lr = wm * 64 + fm * 16 + g16 * 4 + i;
                    ab[(row0 + lr) * 2 + (col - 599)] = acc[fm][fn][i] + bv[fn];
                }
        }
    }

    bf16* stg = (bf16*)smem;                // 64 x 608 bf16 = 77824 B
#pragma unroll
    for (int h = 0; h < 2; ++h) {
        __syncthreads();
        if (wm == h) {
#pragma unroll
            for (int fn = 0; fn < 5; ++fn) {
                int col = wn * 80 + fn * 16 + l16;
                if (col < SPSTRIDE) {
#pragma unroll
                    for (int fm = 0; fm < 4; ++fm)
#pragma unroll
                        for (int i = 0; i < 4; ++i) {
                            int lr = fm * 16 + g16 * 4 + i;
                            stg[lr * SPSTRIDE + col] = (bf16)(acc[fm][fn][i] + bv[fn]);
                        }
                }
            }
        }
        __syncthreads();
#pragma unroll
        for (int it = 0; it < 10; ++it) {         // 64 rows x 152 8B-chunks
            int c = it * 1024 + t;
            if (c < 64 * 152) {
                int r = c >> 7 >> 0; r = c / 152; int k = c - r * 152;
                *(uint64_t*)&sp[(row0 + h * 64 + r) * SPSTRIDE + k * 4] =
                    *(const uint64_t*)&stg[r * SPSTRIDE + k * 4];
            }
        }
    }
}

// ---------------------------------------------------------------------------
// Spline v3 (standalone, proven): register scan -> LDS param tables ->
// binidx scatter -> balanced gather (lane computes 4 outputs j = lane + 50k).
// ---------------------------------------------------------------------------
__global__ __launch_bounds__(256) void spline_kernel(
    const bf16* __restrict__ sp, const float* __restrict__ ab, float* __restrict__ out)
{
    __shared__ float S[4][816];     // per wave: cw@0, ch@204, dd@408, binidx@612
    const int t = threadIdx.x;
    const int lane = t & 63, wid = t >> 6;
    const long row = (long)blockIdx.x * 4 + wid;
    const bf16* spr = sp + row * SPSTRIDE;
    const bool act = lane < 50;
    const float EC = 0.53974247f;                 // log(exp(0.999)-1)
    float* cw = &S[wid][0];
    float* ch = &S[wid][204];
    float* dd = &S[wid][408];
    int*   bx = (int*)&S[wid][612];

    const float sa = __expf(ab[row * 2 + 0]);
    const float sb = ab[row * 2 + 1];

    auto rng = [](float x) -> int {               // first j with tau_j >= x
        int v = (int)ceilf(fmaf(200.f, x, -0.5f));
        return v < 0 ? 0 : (v > 200 ? 200 : v);
    };

    // ---- W logits -> widths -> cw[4l..4l+3] in regs ----
    float p0, p1, p2, p3;
    {
        float x0, x1, x2v, x3;
        if (act) {
            bf16x4 v = *(const bf16x4*)&spr[4 * lane];
            x0 = (float)v[0]; x1 = (float)v[1]; x2v = (float)v[2]; x3 = (float)v[3];
        } else { x0 = x1 = x2v = x3 = -1e30f; }
        float m = fmaxf(fmaxf(x0, x1), fmaxf(x2v, x3));
#pragma unroll
        for (int d = 1; d < 64; d <<= 1) m = fmaxf(m, __shfl_xor(m, d));
        float e0 = act ? __expf(x0 - m) : 0.f;
        float e1 = act ? __expf(x1 - m) : 0.f;
        float e2 = act ? __expf(x2v - m) : 0.f;
        float e3 = act ? __expf(x3 - m) : 0.f;
        float s = e0 + e1 + e2 + e3;
#pragma unroll
        for (int d = 1; d < 64; d <<= 1) s += __shfl_xor(s, d);
        float inv = 0.8f / s;
        p0 = act ? fmaf(e0, inv, 0.001f) : 0.f;
        p1 = act ? fmaf(e1, inv, 0.001f) : 0.f;
        p2 = act ? fmaf(e2, inv, 0.001f) : 0.f;
        p3 = act ? fmaf(e3, inv, 0.001f) : 0.f;
    }
    float c0 = p0, c1 = c0 + p1, c2 = c1 + p2, c3 = c2 + p3;
    float run = c3, ts = run;
#pragma unroll
    for (int d = 1; d < 64; d <<= 1) { float u = __shfl_up(ts, d); if (lane >= d) ts += u; }
    float excl  = ts - run;
    float nexcl = __shfl_down(excl, 1);
    float cwl0 = excl, cwl1 = excl + c0, cwl2 = excl + c1, cwl3 = excl + c2;

    // ---- H logits -> heights -> ch[4l..4l+3] ----
    float hp0, hp1, hp2, hp3;
    {
        float x0, x1, x2v, x3;
        if (act) {
            bf16x4 v = *(const bf16x4*)&spr[200 + 4 * lane];
            x0 = (float)v[0]; x1 = (float)v[1]; x2v = (float)v[2]; x3 = (float)v[3];
        } else { x0 = x1 = x2v = x3 = -1e30f; }
        float m = fmaxf(fmaxf(x0, x1), fmaxf(x2v, x3));
#pragma unroll
        for (int d = 1; d < 64; d <<= 1) m = fmaxf(m, __shfl_xor(m, d));
        float e0 = act ? __expf(x0 - m) : 0.f;
        float e1 = act ? __expf(x1 - m) : 0.f;
        float e2 = act ? __expf(x2v - m) : 0.f;
        float e3 = act ? __expf(x3 - m) : 0.f;
        float s = e0 + e1 + e2 + e3;
#pragma unroll
        for (int d = 1; d < 64; d <<= 1) s += __shfl_xor(s, d);
        float inv = 0.8f / s;
        hp0 = act ? fmaf(e0, inv, 0.001f) : 0.f;
        hp1 = act ? fmaf(e1, inv, 0.001f) : 0.f;
        hp2 = act ? fmaf(e2, inv, 0.001f) : 0.f;
        hp3 = act ? fmaf(e3, inv, 0.001f) : 0.f;
    }
    float hc0 = hp0, hc1 = hc0 + hp1, hc2 = hc1 + hp2, hc3 = hc2 + hp3;
    float hrun = hc3, hts = hrun;
#pragma unroll
    for (int d = 1; d < 64; d <<= 1) { float u = __shfl_up(hts, d); if (lane >= d) hts += u; }
    float hexcl = hts - hrun;
    float ch0 = fmaf(sa, hexcl, sb);
    float ch1 = fmaf(sa, hexcl + hc0, sb);
    float ch2 = fmaf(sa, hexcl + hc1, sb);
    float ch3 = fmaf(sa, hexcl + hc2, sb);

    // ---- D (softplus): dd[4l..4l+3] = {dprev, dv0, dv1, dv2} ----
    float dv0, dv1, dv2, dv3;
    {
        float x0 = 0.f, x1 = 0.f, x2v = 0.f, x3 = 0.f;
        if (act) {
            bf16x4 v = *(const bf16x4*)&spr[400 + 4 * lane];
            x0 = (float)v[0]; x1 = (float)v[1]; x2v = (float)v[2]; x3 = (float)v[3];
        }
        auto spls = [](float x) {
            return fmaxf(x, 0.f) + __logf(1.f + __expf(-fabsf(x))) + 0.001f;
        };
        dv0 = spls(x0); dv1 = spls(x1); dv2 = spls(x2v); dv3 = spls(x3);
    }
    if (lane == 49) dv3 = EC;                     // dd[200] = EDGE
    float dprev = __shfl_up(dv3, 1);
    if (lane == 0) dprev = EC;                    // dd[0] = EDGE

    // ---- write param tables (aligned 16B stores) + tails ----
    if (act) {
        *(f32x4*)&cw[4 * lane] = (f32x4){cwl0, cwl1, cwl2, cwl3};
        *(f32x4*)&ch[4 * lane] = (f32x4){ch0, ch1, ch2, ch3};
        *(f32x4*)&dd[4 * lane] = (f32x4){dprev, dv0, dv1, dv2};
    }
    if (lane == 49) {
        cw[200] = 1.0f;                           // cw[:, -1].set(1.0)
        ch[200] = fmaf(sa, hts, sb);              // sa * total + sb
        dd[200] = EC;
    }

    // ---- scatter bin indices (tiny body; exact partition of [0,200)) ----
    if (act) {
        int b0 = rng(cwl0), b1 = rng(cwl1), b2 = rng(cwl2), b3 = rng(cwl3);
        int b4 = (lane == 49) ? 200 : rng(nexcl);
        for (int j = b0; j < b1; ++j) bx[j] = 4 * lane;
        for (int j = b1; j < b2; ++j) bx[j] = 4 * lane + 1;
        for (int j = b2; j < b3; ++j) bx[j] = 4 * lane + 2;
        for (int j = b3; j < b4; ++j) bx[j] = 4 * lane + 3;
    }
    asm volatile("s_waitcnt lgkmcnt(0)" ::: "memory");   // same-wave LDS RAW

    // ---- balanced gather: lane -> outputs j = lane + 50k ----
    if (act) {
        float* orow = out + (size_t)row * 200;
#pragma unroll
        for (int k = 0; k < 4; ++k) {
            int j = lane + 50 * k;
            int b = bx[j];
            float wl = cw[b], wr = cw[b + 1];
            float hl = ch[b], hr = ch[b + 1];
            float d0 = dd[b], d1 = dd[b + 1];
            float tau = ((float)j + 0.5f) * (1.f / 200.f);
            float w = wr - wl, h = hr - hl;
            float invw = 1.f / w;
            float delta = h * invw;
            float th = (tau - wl) * invw;
            float t1 = th * (1.f - th);
            float numer = h * fmaf(delta * th, th, d0 * t1);
            float denom = fmaf(d0 + d1 - 2.f * delta, t1, delta);
            orow[j] = hl + numer / denom;
        }
    }
}

// ---------------------------------------------------------------------------
// Host launcher
// ---------------------------------------------------------------------------
extern "C" void kernel_launch(void* const* d_in, const int* in_sizes, int n_in,
                              void* d_out, int out_size, void* d_ws, size_t ws_size,
                              hipStream_t stream)
{
    const float* inputs = (const float*)d_in[0];
    const float* W1  = (const float*)d_in[1];
    const float* b1  = (const float*)d_in[2];
    const float* g1  = (const float*)d_in[3];
    const float* be1 = (const float*)d_in[4];
    const float* W2  = (const float*)d_in[5];
    const float* b2  = (const float*)d_in[6];
    const float* g2  = (const float*)d_in[7];
    const float* be2 = (const float*)d_in[8];
    const float* WV  = (const float*)d_in[9];
    const float* bV  = (const float*)d_in[10];
    const float* Wa  = (const float*)d_in[11];
    const float* ba  = (const float*)d_in[12];
    const float* Wb  = (const float*)d_in[13];
    const float* bb  = (const float*)d_in[14];
    float* out = (float*)d_out;

    char* ws = (char*)d_ws;
    bf16*  w1b  = (bf16*) (ws + 0);          //   131072
    bf16*  w2b  = (bf16*) (ws + 131072);     //   524288
    bf16*  wcat = (bf16*) (ws + 655360);     //   655360 (640x512)
    float* bcat = (float*)(ws + 1310720);    //     2560 (640 f32)
    float* ab   = (float*)(ws + 1313280);    //   524288 (B x 2)
    bf16*  x    = (bf16*) (ws + 2097152);    // 67108864 (B x 512)
    bf16*  spb  = (bf16*) (ws + 69206016);   // 79691776 (B x 608)
    bf16*  xin  = (bf16*) (ws + 69206016);   // 16777216 (B x 128) — dead before G3 writes spb

    const int preptot = BATCH * 128 / 8 + 512 * 128 + 512 * 512 + NCAT * 512 + NCAT;
    prep_kernel<<<(preptot + 255) / 256, 256, 0, stream>>>(
        W1, W2, WV, bV, Wa, ba, Wb, bb, inputs, w1b, w2b, wcat, bcat, xin);

    gemm_ln<128><<<BATCH / 128, 1024, 0, stream>>>(xin, w1b, b1, g1, be1, x);
    gemm_ln<512><<<BATCH / 128, 1024, 0, stream>>>(x,   w2b, b2, g2, be2, x);
    gemm_cat<<<BATCH / 128, 1024, 0, stream>>>(x, wcat, bcat, spb, ab);
    spline_kernel<<<BATCH / 4, 256, 0, stream>>>(spb, ab, out);
}

// Round 11
// 263.261 us; speedup vs baseline: 1.3672x; 1.3672x over previous
//
#include <hip/hip_runtime.h>
#include <stdint.h>

typedef __bf16 bf16;
typedef __bf16 bf16x8 __attribute__((ext_vector_type(8)));
typedef __bf16 bf16x4 __attribute__((ext_vector_type(4)));
typedef float  f32x4  __attribute__((ext_vector_type(4)));
typedef uint32_t u32;

#define BATCH    65536
#define NCAT     640      // 599 spline logits + a + b, padded to 640
#define SPSTRIDE 608      // sp row stride: 1216 B = 19 x 64 B

#define MFMA __builtin_amdgcn_mfma_f32_16x16x32_bf16
#define FENCE() asm volatile("" ::: "memory")

// async global->LDS, 16B per lane; LDS dest = wave-uniform base + lane*16
__device__ __forceinline__ void async16(const void* g, void* l) {
    __builtin_amdgcn_global_load_lds(
        (const u32 __attribute__((address_space(1)))*)g,
        (u32 __attribute__((address_space(3)))*)l,
        16, 0, 0);
}

// ---------------------------------------------------------------------------
// Kernel 0: weights -> bf16; Wcat[640][512] = [WV; Wa; Wb; 0]; inputs -> bf16
// ---------------------------------------------------------------------------
__global__ __launch_bounds__(256) void prep_kernel(
    const float* W1, const float* W2, const float* WV,
    const float* bV, const float* Wa, const float* ba,
    const float* Wb, const float* bb, const float* inputs,
    bf16* w1b, bf16* w2b, bf16* wcat, float* bcat, bf16* xin)
{
    int idx = blockIdx.x * 256 + threadIdx.x;
    const int n1 = 512 * 128, n2 = 512 * 512, n3 = NCAT * 512;
    const int n5 = BATCH * 128 / 8;                 // 8 floats per item
    if (idx < n5) {                                  // input cast (bulk) first
        const float4* src = (const float4*)(inputs + idx * 8);
        float4 v0 = src[0], v1 = src[1];
        bf16x8 h;
        h[0]=(bf16)v0.x; h[1]=(bf16)v0.y; h[2]=(bf16)v0.z; h[3]=(bf16)v0.w;
        h[4]=(bf16)v1.x; h[5]=(bf16)v1.y; h[6]=(bf16)v1.z; h[7]=(bf16)v1.w;
        *(bf16x8*)&xin[idx * 8] = h;
        return;
    }
    idx -= n5;
    if (idx < n1) { w1b[idx] = (bf16)W1[idx]; return; }
    idx -= n1;
    if (idx < n2) { w2b[idx] = (bf16)W2[idx]; return; }
    idx -= n2;
    if (idx < n3) {
        int n = idx >> 9, k = idx & 511;
        float v = 0.f;
        if (n < 599)       v = WV[n * 512 + k];
        else if (n == 599) v = Wa[k];
        else if (n == 600) v = Wb[k];
        wcat[idx] = (bf16)v;
        return;
    }
    idx -= n3;
    if (idx < NCAT) {
        float v = 0.f;
        if (idx < 599)       v = bV[idx];
        else if (idx == 599) v = ba[0];
        else if (idx == 600) v = bb[0];
        bcat[idx] = v;
    }
}

// ---------------------------------------------------------------------------
// G1/G2 (round-9 proven): C[128 x 512] = A[128 x K] @ W[512 x K]^T + b
// -> LN -> ReLU -> bf16.  16 waves 4Mx4N, wave tile 32x128 (acc[2][8]).
// B dbuf via global_load_lds; A direct depth-1 prefetch; counted vmcnt(2).
// ---------------------------------------------------------------------------
template <int KDIM>
__global__ __launch_bounds__(1024, 4) void gemm_ln(
    const bf16* __restrict__ A, const bf16* __restrict__ W,
    const float* __restrict__ bias, const float* __restrict__ gamma,
    const float* __restrict__ beta, bf16* out)
{
    __shared__ __align__(16) char smem[65536];      // B dbuf 2x32K; stage-out
    __shared__ float Psum[128][4], Psq[128][4];

    const int t = threadIdx.x;
    const int lane = t & 63, wid = t >> 6;
    const int wm = wid >> 2, wn = wid & 3;
    const int l16 = lane & 15, g16 = lane >> 4;
    const long row0 = (long)blockIdx.x * 128;
    constexpr int NT = KDIM / 32;

    const bf16* arow0 = A + (row0 + wm * 32 + l16) * (long)KDIM + g16 * 8;
    const bf16* arow1 = arow0 + 16 * KDIM;

    f32x4 acc[2][8];
#pragma unroll
    for (int a = 0; a < 2; ++a)
#pragma unroll
        for (int b = 0; b < 8; ++b) acc[a][b] = (f32x4){0.f, 0.f, 0.f, 0.f};

    auto stageB = [&](int kt, int bi) {     // 32 calls of 1KB: 2 per wave
#pragma unroll
        for (int c = 0; c < 2; ++c) {
            int call = c * 16 + wid;
            int row = call * 16 + (lane >> 2);
            const bf16* src = W + (long)row * KDIM + kt * 32 + (lane & 3) * 8;
            async16(src, smem + bi * 32768 + call * 1024);
        }
    };

    stageB(0, 0);
    FENCE();
    bf16x8 af0 = *(const bf16x8*)(arow0);
    bf16x8 af1 = *(const bf16x8*)(arow1);
    asm volatile("s_waitcnt vmcnt(2)\n\ts_barrier" ::: "memory");

    for (int kt = 0; kt < NT; ++kt) {
        const int bi = kt & 1;
        bf16x8 a0 = af0, a1 = af1;
        if (kt + 1 < NT) {
            stageB(kt + 1, bi ^ 1);
            FENCE();
            af0 = *(const bf16x8*)(arow0 + (kt + 1) * 32);
            af1 = *(const bf16x8*)(arow1 + (kt + 1) * 32);
        }
        const bf16* Bb = (const bf16*)(smem + bi * 32768);
#pragma unroll
        for (int fn = 0; fn < 8; ++fn) {
            bf16x8 bv = *(const bf16x8*)(Bb + (wn * 128 + fn * 16 + l16) * 32 + g16 * 8);
            acc[0][fn] = MFMA(a0, bv, acc[0][fn], 0, 0, 0);
            acc[1][fn] = MFMA(a1, bv, acc[1][fn], 0, 0, 0);
        }
        if (kt + 1 < NT)
            asm volatile("s_waitcnt vmcnt(2)\n\ts_barrier" ::: "memory");
    }

    // ---- epilogue: +bias, LN over 512, ReLU -> two-half staged writeout ----
    float gv[8], bev[8];
#pragma unroll
    for (int fn = 0; fn < 8; ++fn) {
        int col = wn * 128 + fn * 16 + l16;
        float bv = bias[col];
        gv[fn] = gamma[col]; bev[fn] = beta[col];
#pragma unroll
        for (int fm = 0; fm < 2; ++fm)
#pragma unroll
            for (int i = 0; i < 4; ++i) acc[fm][fn][i] += bv;
    }
#pragma unroll
    for (int fm = 0; fm < 2; ++fm)
#pragma unroll
        for (int i = 0; i < 4; ++i) {
            float s = 0.f, q = 0.f;
#pragma unroll
            for (int fn = 0; fn < 8; ++fn) { float v = acc[fm][fn][i]; s += v; q += v * v; }
#pragma unroll
            for (int m = 1; m < 16; m <<= 1) { s += __shfl_xor(s, m); q += __shfl_xor(q, m); }
            if (l16 == 0) {
                int lr = wm * 32 + fm * 16 + g16 * 4 + i;
                Psum[lr][wn] = s; Psq[lr][wn] = q;
            }
        }
    __syncthreads();
    float mmean[2][4], mrstd[2][4];
#pragma unroll
    for (int fm = 0; fm < 2; ++fm)
#pragma unroll
        for (int i = 0; i < 4; ++i) {
            int lr = wm * 32 + fm * 16 + g16 * 4 + i;
            float s = Psum[lr][0] + Psum[lr][1] + Psum[lr][2] + Psum[lr][3];
            float q = Psq[lr][0] + Psq[lr][1] + Psq[lr][2] + Psq[lr][3];
            float mean = s * (1.f / 512.f);
            float var  = q * (1.f / 512.f) - mean * mean;
            mmean[fm][i] = mean;
            mrstd[fm][i] = rsqrtf(var + 1e-5f);
        }
    bf16* stg = (bf16*)smem;
#pragma unroll
    for (int h = 0; h < 2; ++h) {
        __syncthreads();
#pragma unroll
        for (int fm = 0; fm < 2; ++fm)
#pragma unroll
            for (int i = 0; i < 4; ++i) {
                int lr = wm * 32 + fm * 16 + g16 * 4 + i;
                if ((lr >> 6) != h) continue;
#pragma unroll
                for (int fn = 0; fn < 8; ++fn) {
                    int col = wn * 128 + fn * 16 + l16;
                    float o = (acc[fm][fn][i] - mmean[fm][i]) * mrstd[fm][i] * gv[fn] + bev[fn];
                    stg[(lr & 63) * 512 + col] = (bf16)fmaxf(o, 0.f);
                }
            }
        __syncthreads();
#pragma unroll
        for (int it = 0; it < 4; ++it) {          // 64 rows x 1KB dense
            int idx = it * 1024 + t;
            *(bf16x8*)&out[(row0 + h * 64 + (idx >> 6)) * 512 + (idx & 63) * 8] =
                *(const bf16x8*)&stg[idx * 8];
        }
    }
}

// ---------------------------------------------------------------------------
// G3: sp-half[128 x 320] = X2[128 x 512] @ Wcat^T + bcat.
// grid = (BATCH/128) x 2 N-halves. 16 waves 4Mx4N, wave tile 32x80
// (acc[2][5]). B TRIPLE-buffered (3x20KB) with DEPTH-2 pipeline: stage(kt+2)
// issued in step kt; counted vmcnt(3) waits only for stage(kt+1).
// Two-half staged dense writeout (sector-exact); ab f32 direct.
// ---------------------------------------------------------------------------
__global__ __launch_bounds__(1024, 4) void gemm_cat(
    const bf16* __restrict__ A, const bf16* __restrict__ W,
    const float* __restrict__ bcat, bf16* __restrict__ sp, float* __restrict__ ab)
{
    __shared__ __align__(16) char smem[61440];      // B 3x20K; stage-out 40K

    const int t = threadIdx.x;
    const int lane = t & 63, wid = t >> 6;
    const int wm = wid >> 2, wn = wid & 3;
    const int l16 = lane & 15, g16 = lane >> 4;
    const int nh  = blockIdx.x & 1;                  // N-half: cols [320nh, ..)
    const long row0 = (long)(blockIdx.x >> 1) * 128;

    const bf16* arow0 = A + (row0 + wm * 32 + l16) * 512 + g16 * 8;
    const bf16* arow1 = arow0 + 16 * 512;

    f32x4 acc[2][5];
#pragma unroll
    for (int a = 0; a < 2; ++a)
#pragma unroll
        for (int b = 0; b < 5; ++b) acc[a][b] = (f32x4){0.f, 0.f, 0.f, 0.f};

    auto stageB = [&](int kt, int bi) {     // 20 calls of 1KB: 1-2 per wave
#pragma unroll
        for (int c = 0; c < 2; ++c) {
            int call = c * 16 + wid;
            if (call < 20) {
                int row = nh * 320 + call * 16 + (lane >> 2);
                const bf16* src = W + (long)row * 512 + kt * 32 + (lane & 3) * 8;
                async16(src, smem + bi * 20480 + call * 1024);
            }
        }
    };

    stageB(0, 0);
    stageB(1, 1);
    FENCE();
    bf16x8 af0 = *(const bf16x8*)(arow0);
    bf16x8 af1 = *(const bf16x8*)(arow1);
    // drain stage(0) only; stage(1) + A(0) stay in flight
    asm volatile("s_waitcnt vmcnt(3)\n\ts_barrier" ::: "memory");

#pragma unroll
    for (int kt = 0; kt < 16; ++kt) {
        const int cur = kt % 3;
        bf16x8 a0 = af0, a1 = af1;
        if (kt + 2 < 16) { stageB(kt + 2, (kt + 2) % 3); FENCE(); }
        if (kt + 1 < 16) {
            af0 = *(const bf16x8*)(arow0 + (kt + 1) * 32);
            af1 = *(const bf16x8*)(arow1 + (kt + 1) * 32);
        }
        const bf16* Bb = (const bf16*)(smem + cur * 20480);
#pragma unroll
        for (int fn = 0; fn < 5; ++fn) {
            bf16x8 bv = *(const bf16x8*)(Bb + (wn * 80 + fn * 16 + l16) * 32 + g16 * 8);
            acc[0][fn] = MFMA(a0, bv, acc[0][fn], 0, 0, 0);
            acc[1][fn] = MFMA(a1, bv, acc[1][fn], 0, 0, 0);
        }
        // drain stage(kt+1); keep stage(kt+2) + A(kt+1) in flight
        if (kt + 2 < 16)
            asm volatile("s_waitcnt vmcnt(3)\n\ts_barrier" ::: "memory");
        else if (kt + 1 < 16)
            asm volatile("s_waitcnt vmcnt(2)\n\ts_barrier" ::: "memory");
    }
    __syncthreads();                        // full drain; B bufs dead

    // ---- +bcat; ab f32 direct (cols 599/600 live in nh==1) ----
    float bv[5];
#pragma unroll
    for (int fn = 0; fn < 5; ++fn) bv[fn] = bcat[nh * 320 + wn * 80 + fn * 16 + l16];

    if (nh == 1) {
#pragma unroll
        for (int fn = 0; fn < 5; ++fn) {
            int col = 320 + wn * 80 + fn * 16 + l16;
            if (col == 599 || col == 600) {
#pragma unroll
                for (int fm = 0; fm < 2; ++fm)
#pragma unroll
                    for (int i = 0; i < 4; ++i) {
                        int lr = wm * 32 + fm * 16 + g16 * 4 + i;
                        ab[(row0 + lr) * 2 + (col - 599)] = acc[fm][fn][i] + bv[fn];
                    }
            }
        }
    }

    bf16* stg = (bf16*)smem;                // [64][320] = 40960 B
#pragma unroll
    for (int h = 0; h < 2; ++h) {
        __syncthreads();
        if ((wm >> 1) == h) {
#pragma unroll
            for (int fn = 0; fn < 5; ++fn) {
                int lcol = wn * 80 + fn * 16 + l16;
#pragma unroll
                for (int fm = 0; fm < 2; ++fm)
#pragma unroll
                    for (int i = 0; i < 4; ++i) {
                        int lr = (wm & 1) * 32 + fm * 16 + g16 * 4 + i;
                        stg[lr * 320 + lcol] = (bf16)(acc[fm][fn][i] + bv[fn]);
                    }
            }
        }
        __syncthreads();
        if (nh == 0) {                       // cols 0..319: 80 8B-chunks/row
            for (int c = t; c < 64 * 80; c += 1024) {
                int r = c / 80, k = c - r * 80;
                *(uint64_t*)&sp[(row0 + h * 64 + r) * SPSTRIDE + k * 4] =
                    *(const uint64_t*)&stg[r * 320 + k * 4];
            }
        } else {                             // cols 320..607: 72 chunks/row
            for (int c = t; c < 64 * 72; c += 1024) {
                int r = c / 72, k = c - r * 72;
                *(uint64_t*)&sp[(row0 + h * 64 + r) * SPSTRIDE + 320 + k * 4] =
                    *(const uint64_t*)&stg[r * 320 + k * 4];
            }
        }
    }
}

// ---------------------------------------------------------------------------
// Spline v3 (standalone, proven): register scan -> LDS param tables ->
// binidx scatter -> balanced gather (lane computes 4 outputs j = lane + 50k).
// ---------------------------------------------------------------------------
__global__ __launch_bounds__(256) void spline_kernel(
    const bf16* __restrict__ sp, const float* __restrict__ ab, float* __restrict__ out)
{
    __shared__ float S[4][816];     // per wave: cw@0, ch@204, dd@408, binidx@612
    const int t = threadIdx.x;
    const int lane = t & 63, wid = t >> 6;
    const long row = (long)blockIdx.x * 4 + wid;
    const bf16* spr = sp + row * SPSTRIDE;
    const bool act = lane < 50;
    const float EC = 0.53974247f;                 // log(exp(0.999)-1)
    float* cw = &S[wid][0];
    float* ch = &S[wid][204];
    float* dd = &S[wid][408];
    int*   bx = (int*)&S[wid][612];

    const float sa = __expf(ab[row * 2 + 0]);
    const float sb = ab[row * 2 + 1];

    auto rng = [](float x) -> int {               // first j with tau_j >= x
        int v = (int)ceilf(fmaf(200.f, x, -0.5f));
        return v < 0 ? 0 : (v > 200 ? 200 : v);
    };

    // ---- W logits -> widths -> cw[4l..4l+3] in regs ----
    float p0, p1, p2, p3;
    {
        float x0, x1, x2v, x3;
        if (act) {
            bf16x4 v = *(const bf16x4*)&spr[4 * lane];
            x0 = (float)v[0]; x1 = (float)v[1]; x2v = (float)v[2]; x3 = (float)v[3];
        } else { x0 = x1 = x2v = x3 = -1e30f; }
        float m = fmaxf(fmaxf(x0, x1), fmaxf(x2v, x3));
#pragma unroll
        for (int d = 1; d < 64; d <<= 1) m = fmaxf(m, __shfl_xor(m, d));
        float e0 = act ? __expf(x0 - m) : 0.f;
        float e1 = act ? __expf(x1 - m) : 0.f;
        float e2 = act ? __expf(x2v - m) : 0.f;
        float e3 = act ? __expf(x3 - m) : 0.f;
        float s = e0 + e1 + e2 + e3;
#pragma unroll
        for (int d = 1; d < 64; d <<= 1) s += __shfl_xor(s, d);
        float inv = 0.8f / s;
        p0 = act ? fmaf(e0, inv, 0.001f) : 0.f;
        p1 = act ? fmaf(e1, inv, 0.001f) : 0.f;
        p2 = act ? fmaf(e2, inv, 0.001f) : 0.f;
        p3 = act ? fmaf(e3, inv, 0.001f) : 0.f;
    }
    float c0 = p0, c1 = c0 + p1, c2 = c1 + p2, c3 = c2 + p3;
    float run = c3, ts = run;
#pragma unroll
    for (int d = 1; d < 64; d <<= 1) { float u = __shfl_up(ts, d); if (lane >= d) ts += u; }
    float excl  = ts - run;
    float nexcl = __shfl_down(excl, 1);
    float cwl0 = excl, cwl1 = excl + c0, cwl2 = excl + c1, cwl3 = excl + c2;

    // ---- H logits -> heights -> ch[4l..4l+3] ----
    float hp0, hp1, hp2, hp3;
    {
        float x0, x1, x2v, x3;
        if (act) {
            bf16x4 v = *(const bf16x4*)&spr[200 + 4 * lane];
            x0 = (float)v[0]; x1 = (float)v[1]; x2v = (float)v[2]; x3 = (float)v[3];
        } else { x0 = x1 = x2v = x3 = -1e30f; }
        float m = fmaxf(fmaxf(x0, x1), fmaxf(x2v, x3));
#pragma unroll
        for (int d = 1; d < 64; d <<= 1) m = fmaxf(m, __shfl_xor(m, d));
        float e0 = act ? __expf(x0 - m) : 0.f;
        float e1 = act ? __expf(x1 - m) : 0.f;
        float e2 = act ? __expf(x2v - m) : 0.f;
        float e3 = act ? __expf(x3 - m) : 0.f;
        float s = e0 + e1 + e2 + e3;
#pragma unroll
        for (int d = 1; d < 64; d <<= 1) s += __shfl_xor(s, d);
        float inv = 0.8f / s;
        hp0 = act ? fmaf(e0, inv, 0.001f) : 0.f;
        hp1 = act ? fmaf(e1, inv, 0.001f) : 0.f;
        hp2 = act ? fmaf(e2, inv, 0.001f) : 0.f;
        hp3 = act ? fmaf(e3, inv, 0.001f) : 0.f;
    }
    float hc0 = hp0, hc1 = hc0 + hp1, hc2 = hc1 + hp2, hc3 = hc2 + hp3;
    float hrun = hc3, hts = hrun;
#pragma unroll
    for (int d = 1; d < 64; d <<= 1) { float u = __shfl_up(hts, d); if (lane >= d) hts += u; }
    float hexcl = hts - hrun;
    float ch0 = fmaf(sa, hexcl, sb);
    float ch1 = fmaf(sa, hexcl + hc0, sb);
    float ch2 = fmaf(sa, hexcl + hc1, sb);
    float ch3 = fmaf(sa, hexcl + hc2, sb);

    // ---- D (softplus): dd[4l..4l+3] = {dprev, dv0, dv1, dv2} ----
    float dv0, dv1, dv2, dv3;
    {
        float x0 = 0.f, x1 = 0.f, x2v = 0.f, x3 = 0.f;
        if (act) {
            bf16x4 v = *(const bf16x4*)&spr[400 + 4 * lane];
            x0 = (float)v[0]; x1 = (float)v[1]; x2v = (float)v[2]; x3 = (float)v[3];
        }
        auto spls = [](float x) {
            return fmaxf(x, 0.f) + __logf(1.f + __expf(-fabsf(x))) + 0.001f;
        };
        dv0 = spls(x0); dv1 = spls(x1); dv2 = spls(x2v); dv3 = spls(x3);
    }
    if (lane == 49) dv3 = EC;                     // dd[200] = EDGE
    float dprev = __shfl_up(dv3, 1);
    if (lane == 0) dprev = EC;                    // dd[0] = EDGE

    // ---- write param tables (aligned 16B stores) + tails ----
    if (act) {
        *(f32x4*)&cw[4 * lane] = (f32x4){cwl0, cwl1, cwl2, cwl3};
        *(f32x4*)&ch[4 * lane] = (f32x4){ch0, ch1, ch2, ch3};
        *(f32x4*)&dd[4 * lane] = (f32x4){dprev, dv0, dv1, dv2};
    }
    if (lane == 49) {
        cw[200] = 1.0f;                           // cw[:, -1].set(1.0)
        ch[200] = fmaf(sa, hts, sb);              // sa * total + sb
        dd[200] = EC;
    }

    // ---- scatter bin indices (tiny body; exact partition of [0,200)) ----
    if (act) {
        int b0 = rng(cwl0), b1 = rng(cwl1), b2 = rng(cwl2), b3 = rng(cwl3);
        int b4 = (lane == 49) ? 200 : rng(nexcl);
        for (int j = b0; j < b1; ++j) bx[j] = 4 * lane;
        for (int j = b1; j < b2; ++j) bx[j] = 4 * lane + 1;
        for (int j = b2; j < b3; ++j) bx[j] = 4 * lane + 2;
        for (int j = b3; j < b4; ++j) bx[j] = 4 * lane + 3;
    }
    asm volatile("s_waitcnt lgkmcnt(0)" ::: "memory");   // same-wave LDS RAW

    // ---- balanced gather: lane -> outputs j = lane + 50k ----
    if (act) {
        float* orow = out + (size_t)row * 200;
#pragma unroll
        for (int k = 0; k < 4; ++k) {
            int j = lane + 50 * k;
            int b = bx[j];
            float wl = cw[b], wr = cw[b + 1];
            float hl = ch[b], hr = ch[b + 1];
            float d0 = dd[b], d1 = dd[b + 1];
            float tau = ((float)j + 0.5f) * (1.f / 200.f);
            float w = wr - wl, h = hr - hl;
            float invw = 1.f / w;
            float delta = h * invw;
            float th = (tau - wl) * invw;
            float t1 = th * (1.f - th);
            float numer = h * fmaf(delta * th, th, d0 * t1);
            float denom = fmaf(d0 + d1 - 2.f * delta, t1, delta);
            orow[j] = hl + numer / denom;
        }
    }
}

// ---------------------------------------------------------------------------
// Host launcher
// ---------------------------------------------------------------------------
extern "C" void kernel_launch(void* const* d_in, const int* in_sizes, int n_in,
                              void* d_out, int out_size, void* d_ws, size_t ws_size,
                              hipStream_t stream)
{
    const float* inputs = (const float*)d_in[0];
    const float* W1  = (const float*)d_in[1];
    const float* b1  = (const float*)d_in[2];
    const float* g1  = (const float*)d_in[3];
    const float* be1 = (const float*)d_in[4];
    const float* W2  = (const float*)d_in[5];
    const float* b2  = (const float*)d_in[6];
    const float* g2  = (const float*)d_in[7];
    const float* be2 = (const float*)d_in[8];
    const float* WV  = (const float*)d_in[9];
    const float* bV  = (const float*)d_in[10];
    const float* Wa  = (const float*)d_in[11];
    const float* ba  = (const float*)d_in[12];
    const float* Wb  = (const float*)d_in[13];
    const float* bb  = (const float*)d_in[14];
    float* out = (float*)d_out;

    char* ws = (char*)d_ws;
    bf16*  w1b  = (bf16*) (ws + 0);          //   131072
    bf16*  w2b  = (bf16*) (ws + 131072);     //   524288
    bf16*  wcat = (bf16*) (ws + 655360);     //   655360 (640x512)
    float* bcat = (float*)(ws + 1310720);    //     2560 (640 f32)
    float* ab   = (float*)(ws + 1313280);    //   524288 (B x 2)
    bf16*  x    = (bf16*) (ws + 2097152);    // 67108864 (B x 512)
    bf16*  spb  = (bf16*) (ws + 69206016);   // 79691776 (B x 608)
    bf16*  xin  = (bf16*) (ws + 69206016);   // 16777216 (B x 128) — dead before G3 writes spb

    const int preptot = BATCH * 128 / 8 + 512 * 128 + 512 * 512 + NCAT * 512 + NCAT;
    prep_kernel<<<(preptot + 255) / 256, 256, 0, stream>>>(
        W1, W2, WV, bV, Wa, ba, Wb, bb, inputs, w1b, w2b, wcat, bcat, xin);

    gemm_ln<128><<<BATCH / 128, 1024, 0, stream>>>(xin, w1b, b1, g1, be1, x);
    gemm_ln<512><<<BATCH / 128, 1024, 0, stream>>>(x,   w2b, b2, g2, be2, x);
    gemm_cat<<<(BATCH / 128) * 2, 1024, 0, stream>>>(x, wcat, bcat, spb, ab);
    spline_kernel<<<BATCH / 4, 256, 0, stream>>>(spb, ab, out);
}

// Round 12
// 263.056 us; speedup vs baseline: 1.3682x; 1.0008x over previous
//
#include <hip/hip_runtime.h>
#include <stdint.h>

typedef __bf16 bf16;
typedef __bf16 bf16x8 __attribute__((ext_vector_type(8)));
typedef __bf16 bf16x4 __attribute__((ext_vector_type(4)));
typedef float  f32x4  __attribute__((ext_vector_type(4)));
typedef uint32_t u32;

#define BATCH    65536
#define NCAT     640      // 599 spline logits + a + b, padded to 640
#define SPSTRIDE 608      // sp row stride: 1216 B = 19 x 64 B

#define MFMA __builtin_amdgcn_mfma_f32_16x16x32_bf16
#define FENCE() asm volatile("" ::: "memory")

// async global->LDS, 16B per lane; LDS dest = wave-uniform base + lane*16
__device__ __forceinline__ void async16(const void* g, void* l) {
    __builtin_amdgcn_global_load_lds(
        (const u32 __attribute__((address_space(1)))*)g,
        (u32 __attribute__((address_space(3)))*)l,
        16, 0, 0);
}

// ---------------------------------------------------------------------------
// Kernel 0: weights -> bf16; Wcat[640][512] = [WV; Wa; Wb; 0]; inputs -> bf16
// ---------------------------------------------------------------------------
__global__ __launch_bounds__(256) void prep_kernel(
    const float* W1, const float* W2, const float* WV,
    const float* bV, const float* Wa, const float* ba,
    const float* Wb, const float* bb, const float* inputs,
    bf16* w1b, bf16* w2b, bf16* wcat, float* bcat, bf16* xin)
{
    int idx = blockIdx.x * 256 + threadIdx.x;
    const int n1 = 512 * 128, n2 = 512 * 512, n3 = NCAT * 512;
    const int n5 = BATCH * 128 / 8;                 // 8 floats per item
    if (idx < n5) {                                  // input cast (bulk) first
        const float4* src = (const float4*)(inputs + idx * 8);
        float4 v0 = src[0], v1 = src[1];
        bf16x8 h;
        h[0]=(bf16)v0.x; h[1]=(bf16)v0.y; h[2]=(bf16)v0.z; h[3]=(bf16)v0.w;
        h[4]=(bf16)v1.x; h[5]=(bf16)v1.y; h[6]=(bf16)v1.z; h[7]=(bf16)v1.w;
        *(bf16x8*)&xin[idx * 8] = h;
        return;
    }
    idx -= n5;
    if (idx < n1) { w1b[idx] = (bf16)W1[idx]; return; }
    idx -= n1;
    if (idx < n2) { w2b[idx] = (bf16)W2[idx]; return; }
    idx -= n2;
    if (idx < n3) {
        int n = idx >> 9, k = idx & 511;
        float v = 0.f;
        if (n < 599)       v = WV[n * 512 + k];
        else if (n == 599) v = Wa[k];
        else if (n == 600) v = Wb[k];
        wcat[idx] = (bf16)v;
        return;
    }
    idx -= n3;
    if (idx < NCAT) {
        float v = 0.f;
        if (idx < 599)       v = bV[idx];
        else if (idx == 599) v = ba[0];
        else if (idx == 600) v = bb[0];
        bcat[idx] = v;
    }
}

// ---------------------------------------------------------------------------
// G1/G2 (round-9 proven): C[128 x 512] = A[128 x K] @ W[512 x K]^T + b
// -> LN -> ReLU -> bf16.  16 waves 4Mx4N, wave tile 32x128 (acc[2][8]).
// B dbuf via global_load_lds; A direct depth-1 prefetch; counted vmcnt(2).
// ---------------------------------------------------------------------------
template <int KDIM>
__global__ __launch_bounds__(1024, 4) void gemm_ln(
    const bf16* __restrict__ A, const bf16* __restrict__ W,
    const float* __restrict__ bias, const float* __restrict__ gamma,
    const float* __restrict__ beta, bf16* out)
{
    __shared__ __align__(16) char smem[65536];      // B dbuf 2x32K; stage-out
    __shared__ float Psum[128][4], Psq[128][4];

    const int t = threadIdx.x;
    const int lane = t & 63, wid = t >> 6;
    const int wm = wid >> 2, wn = wid & 3;
    const int l16 = lane & 15, g16 = lane >> 4;
    const long row0 = (long)blockIdx.x * 128;
    constexpr int NT = KDIM / 32;

    const bf16* arow0 = A + (row0 + wm * 32 + l16) * (long)KDIM + g16 * 8;
    const bf16* arow1 = arow0 + 16 * KDIM;

    f32x4 acc[2][8];
#pragma unroll
    for (int a = 0; a < 2; ++a)
#pragma unroll
        for (int b = 0; b < 8; ++b) acc[a][b] = (f32x4){0.f, 0.f, 0.f, 0.f};

    auto stageB = [&](int kt, int bi) {     // 32 calls of 1KB: 2 per wave
#pragma unroll
        for (int c = 0; c < 2; ++c) {
            int call = c * 16 + wid;
            int row = call * 16 + (lane >> 2);
            const bf16* src = W + (long)row * KDIM + kt * 32 + (lane & 3) * 8;
            async16(src, smem + bi * 32768 + call * 1024);
        }
    };

    stageB(0, 0);
    FENCE();
    bf16x8 af0 = *(const bf16x8*)(arow0);
    bf16x8 af1 = *(const bf16x8*)(arow1);
    asm volatile("s_waitcnt vmcnt(2)\n\ts_barrier" ::: "memory");

    for (int kt = 0; kt < NT; ++kt) {
        const int bi = kt & 1;
        bf16x8 a0 = af0, a1 = af1;
        if (kt + 1 < NT) {
            stageB(kt + 1, bi ^ 1);
            FENCE();
            af0 = *(const bf16x8*)(arow0 + (kt + 1) * 32);
            af1 = *(const bf16x8*)(arow1 + (kt + 1) * 32);
        }
        const bf16* Bb = (const bf16*)(smem + bi * 32768);
#pragma unroll
        for (int fn = 0; fn < 8; ++fn) {
            bf16x8 bv = *(const bf16x8*)(Bb + (wn * 128 + fn * 16 + l16) * 32 + g16 * 8);
            acc[0][fn] = MFMA(a0, bv, acc[0][fn], 0, 0, 0);
            acc[1][fn] = MFMA(a1, bv, acc[1][fn], 0, 0, 0);
        }
        if (kt + 1 < NT)
            asm volatile("s_waitcnt vmcnt(2)\n\ts_barrier" ::: "memory");
    }

    // ---- epilogue: +bias, LN over 512, ReLU -> two-half staged writeout ----
    float gv[8], bev[8];
#pragma unroll
    for (int fn = 0; fn < 8; ++fn) {
        int col = wn * 128 + fn * 16 + l16;
        float bv = bias[col];
        gv[fn] = gamma[col]; bev[fn] = beta[col];
#pragma unroll
        for (int fm = 0; fm < 2; ++fm)
#pragma unroll
            for (int i = 0; i < 4; ++i) acc[fm][fn][i] += bv;
    }
#pragma unroll
    for (int fm = 0; fm < 2; ++fm)
#pragma unroll
        for (int i = 0; i < 4; ++i) {
            float s = 0.f, q = 0.f;
#pragma unroll
            for (int fn = 0; fn < 8; ++fn) { float v = acc[fm][fn][i]; s += v; q += v * v; }
#pragma unroll
            for (int m = 1; m < 16; m <<= 1) { s += __shfl_xor(s, m); q += __shfl_xor(q, m); }
            if (l16 == 0) {
                int lr = wm * 32 + fm * 16 + g16 * 4 + i;
                Psum[lr][wn] = s; Psq[lr][wn] = q;
            }
        }
    __syncthreads();
    float mmean[2][4], mrstd[2][4];
#pragma unroll
    for (int fm = 0; fm < 2; ++fm)
#pragma unroll
        for (int i = 0; i < 4; ++i) {
            int lr = wm * 32 + fm * 16 + g16 * 4 + i;
            float s = Psum[lr][0] + Psum[lr][1] + Psum[lr][2] + Psum[lr][3];
            float q = Psq[lr][0] + Psq[lr][1] + Psq[lr][2] + Psq[lr][3];
            float mean = s * (1.f / 512.f);
            float var  = q * (1.f / 512.f) - mean * mean;
            mmean[fm][i] = mean;
            mrstd[fm][i] = rsqrtf(var + 1e-5f);
        }
    bf16* stg = (bf16*)smem;
#pragma unroll
    for (int h = 0; h < 2; ++h) {
        __syncthreads();
#pragma unroll
        for (int fm = 0; fm < 2; ++fm)
#pragma unroll
            for (int i = 0; i < 4; ++i) {
                int lr = wm * 32 + fm * 16 + g16 * 4 + i;
                if ((lr >> 6) != h) continue;
#pragma unroll
                for (int fn = 0; fn < 8; ++fn) {
                    int col = wn * 128 + fn * 16 + l16;
                    float o = (acc[fm][fn][i] - mmean[fm][i]) * mrstd[fm][i] * gv[fn] + bev[fn];
                    stg[(lr & 63) * 512 + col] = (bf16)fmaxf(o, 0.f);
                }
            }
        __syncthreads();
#pragma unroll
        for (int it = 0; it < 4; ++it) {          // 64 rows x 1KB dense
            int idx = it * 1024 + t;
            *(bf16x8*)&out[(row0 + h * 64 + (idx >> 6)) * 512 + (idx & 63) * 8] =
                *(const bf16x8*)&stg[idx * 8];
        }
    }
}

// ---------------------------------------------------------------------------
// G3: sp-half[128 x 320] = X2[128 x 512] @ Wcat^T + bcat.
// grid = (BATCH/128) x 2 N-halves. 16 waves 4Mx4N, wave tile 32x80
// (acc[2][5]). B TRIPLE-buffered (3x20KB) with DEPTH-2 pipeline: stage(kt+2)
// issued in step kt; counted vmcnt(3) waits only for stage(kt+1).
// Two-half staged dense writeout (sector-exact); ab f32 direct.
// ---------------------------------------------------------------------------
__global__ __launch_bounds__(1024, 4) void gemm_cat(
    const bf16* __restrict__ A, const bf16* __restrict__ W,
    const float* __restrict__ bcat, bf16* __restrict__ sp, float* __restrict__ ab)
{
    __shared__ __align__(16) char smem[61440];      // B 3x20K; stage-out 40K

    const int t = threadIdx.x;
    const int lane = t & 63, wid = t >> 6;
    const int wm = wid >> 2, wn = wid & 3;
    const int l16 = lane & 15, g16 = lane >> 4;
    const int nh  = blockIdx.x & 1;                  // N-half: cols [320nh, ..)
    const long row0 = (long)(blockIdx.x >> 1) * 128;

    const bf16* arow0 = A + (row0 + wm * 32 + l16) * 512 + g16 * 8;
    const bf16* arow1 = arow0 + 16 * 512;

    f32x4 acc[2][5];
#pragma unroll
    for (int a = 0; a < 2; ++a)
#pragma unroll
        for (int b = 0; b < 5; ++b) acc[a][b] = (f32x4){0.f, 0.f, 0.f, 0.f};

    auto stageB = [&](int kt, int bi) {     // 20 calls of 1KB: 1-2 per wave
#pragma unroll
        for (int c = 0; c < 2; ++c) {
            int call = c * 16 + wid;
            if (call < 20) {
                int row = nh * 320 + call * 16 + (lane >> 2);
                const bf16* src = W + (long)row * 512 + kt * 32 + (lane & 3) * 8;
                async16(src, smem + bi * 20480 + call * 1024);
            }
        }
    };

    stageB(0, 0);
    stageB(1, 1);
    FENCE();
    bf16x8 af0 = *(const bf16x8*)(arow0);
    bf16x8 af1 = *(const bf16x8*)(arow1);
    // drain stage(0) only; stage(1) + A(0) stay in flight
    asm volatile("s_waitcnt vmcnt(3)\n\ts_barrier" ::: "memory");

#pragma unroll
    for (int kt = 0; kt < 16; ++kt) {
        const int cur = kt % 3;
        bf16x8 a0 = af0, a1 = af1;
        if (kt + 2 < 16) { stageB(kt + 2, (kt + 2) % 3); FENCE(); }
        if (kt + 1 < 16) {
            af0 = *(const bf16x8*)(arow0 + (kt + 1) * 32);
            af1 = *(const bf16x8*)(arow1 + (kt + 1) * 32);
        }
        const bf16* Bb = (const bf16*)(smem + cur * 20480);
#pragma unroll
        for (int fn = 0; fn < 5; ++fn) {
            bf16x8 bv = *(const bf16x8*)(Bb + (wn * 80 + fn * 16 + l16) * 32 + g16 * 8);
            acc[0][fn] = MFMA(a0, bv, acc[0][fn], 0, 0, 0);
            acc[1][fn] = MFMA(a1, bv, acc[1][fn], 0, 0, 0);
        }
        // drain stage(kt+1); keep stage(kt+2) + A(kt+1) in flight
        if (kt + 2 < 16)
            asm volatile("s_waitcnt vmcnt(3)\n\ts_barrier" ::: "memory");
        else if (kt + 1 < 16)
            asm volatile("s_waitcnt vmcnt(2)\n\ts_barrier" ::: "memory");
    }
    __syncthreads();                        // full drain; B bufs dead

    // ---- +bcat; ab f32 direct (cols 599/600 live in nh==1) ----
    float bv[5];
#pragma unroll
    for (int fn = 0; fn < 5; ++fn) bv[fn] = bcat[nh * 320 + wn * 80 + fn * 16 + l16];

    if (nh == 1) {
#pragma unroll
        for (int fn = 0; fn < 5; ++fn) {
            int col = 320 + wn * 80 + fn * 16 + l16;
            if (col == 599 || col == 600) {
#pragma unroll
                for (int fm = 0; fm < 2; ++fm)
#pragma unroll
                    for (int i = 0; i < 4; ++i) {
                        int lr = wm * 32 + fm * 16 + g16 * 4 + i;
                        ab[(row0 + lr) * 2 + (col - 599)] = acc[fm][fn][i] + bv[fn];
                    }
            }
        }
    }

    bf16* stg = (bf16*)smem;                // [64][320] = 40960 B
#pragma unroll
    for (int h = 0; h < 2; ++h) {
        __syncthreads();
        if ((wm >> 1) == h) {
#pragma unroll
            for (int fn = 0; fn < 5; ++fn) {
                int lcol = wn * 80 + fn * 16 + l16;
#pragma unroll
                for (int fm = 0; fm < 2; ++fm)
#pragma unroll
                    for (int i = 0; i < 4; ++i) {
                        int lr = (wm & 1) * 32 + fm * 16 + g16 * 4 + i;
                        stg[lr * 320 + lcol] = (bf16)(acc[fm][fn][i] + bv[fn]);
                    }
            }
        }
        __syncthreads();
        if (nh == 0) {                       // cols 0..319: 80 8B-chunks/row
            for (int c = t; c < 64 * 80; c += 1024) {
                int r = c / 80, k = c - r * 80;
                *(uint64_t*)&sp[(row0 + h * 64 + r) * SPSTRIDE + k * 4] =
                    *(const uint64_t*)&stg[r * 320 + k * 4];
            }
        } else {                             // cols 320..607: 72 chunks/row
            for (int c = t; c < 64 * 72; c += 1024) {
                int r = c / 72, k = c - r * 72;
                *(uint64_t*)&sp[(row0 + h * 64 + r) * SPSTRIDE + 320 + k * 4] =
                    *(const uint64_t*)&stg[r * 320 + k * 4];
            }
        }
    }
}

// ---------------------------------------------------------------------------
// Spline v3 (standalone, proven): register scan -> LDS param tables ->
// binidx scatter -> balanced gather (lane computes 4 outputs j = lane + 50k).
// ---------------------------------------------------------------------------
__global__ __launch_bounds__(256) void spline_kernel(
    const bf16* __restrict__ sp, const float* __restrict__ ab, float* __restrict__ out)
{
    __shared__ float S[4][816];     // per wave: cw@0, ch@204, dd@408, binidx@612
    const int t = threadIdx.x;
    const int lane = t & 63, wid = t >> 6;
    const long row = (long)blockIdx.x * 4 + wid;
    const bf16* spr = sp + row * SPSTRIDE;
    const bool act = lane < 50;
    const float EC = 0.53974247f;                 // log(exp(0.999)-1)
    float* cw = &S[wid][0];
    float* ch = &S[wid][204];
    float* dd = &S[wid][408];
    int*   bx = (int*)&S[wid][612];

    const float sa = __expf(ab[row * 2 + 0]);
    const float sb = ab[row * 2 + 1];

    auto rng = [](float x) -> int {               // first j with tau_j >= x
        int v = (int)ceilf(fmaf(200.f, x, -0.5f));
        return v < 0 ? 0 : (v > 200 ? 200 : v);
    };

    // ---- W logits -> widths -> cw[4l..4l+3] in regs ----
    float p0, p1, p2, p3;
    {
        float x0, x1, x2v, x3;
        if (act) {
            bf16x4 v = *(const bf16x4*)&spr[4 * lane];
            x0 = (float)v[0]; x1 = (float)v[1]; x2v = (float)v[2]; x3 = (float)v[3];
        } else { x0 = x1 = x2v = x3 = -1e30f; }
        float m = fmaxf(fmaxf(x0, x1), fmaxf(x2v, x3));
#pragma unroll
        for (int d = 1; d < 64; d <<= 1) m = fmaxf(m, __shfl_xor(m, d));
        float e0 = act ? __expf(x0 - m) : 0.f;
        float e1 = act ? __expf(x1 - m) : 0.f;
        float e2 = act ? __expf(x2v - m) : 0.f;
        float e3 = act ? __expf(x3 - m) : 0.f;
        float s = e0 + e1 + e2 + e3;
#pragma unroll
        for (int d = 1; d < 64; d <<= 1) s += __shfl_xor(s, d);
        float inv = 0.8f / s;
        p0 = act ? fmaf(e0, inv, 0.001f) : 0.f;
        p1 = act ? fmaf(e1, inv, 0.001f) : 0.f;
        p2 = act ? fmaf(e2, inv, 0.001f) : 0.f;
        p3 = act ? fmaf(e3, inv, 0.001f) : 0.f;
    }
    float c0 = p0, c1 = c0 + p1, c2 = c1 + p2, c3 = c2 + p3;
    float run = c3, ts = run;
#pragma unroll
    for (int d = 1; d < 64; d <<= 1) { float u = __shfl_up(ts, d); if (lane >= d) ts += u; }
    float excl  = ts - run;
    float nexcl = __shfl_down(excl, 1);
    float cwl0 = excl, cwl1 = excl + c0, cwl2 = excl + c1, cwl3 = excl + c2;

    // ---- H logits -> heights -> ch[4l..4l+3] ----
    float hp0, hp1, hp2, hp3;
    {
        float x0, x1, x2v, x3;
        if (act) {
            bf16x4 v = *(const bf16x4*)&spr[200 + 4 * lane];
            x0 = (float)v[0]; x1 = (float)v[1]; x2v = (float)v[2]; x3 = (float)v[3];
        } else { x0 = x1 = x2v = x3 = -1e30f; }
        float m = fmaxf(fmaxf(x0, x1), fmaxf(x2v, x3));
#pragma unroll
        for (int d = 1; d < 64; d <<= 1) m = fmaxf(m, __shfl_xor(m, d));
        float e0 = act ? __expf(x0 - m) : 0.f;
        float e1 = act ? __expf(x1 - m) : 0.f;
        float e2 = act ? __expf(x2v - m) : 0.f;
        float e3 = act ? __expf(x3 - m) : 0.f;
        float s = e0 + e1 + e2 + e3;
#pragma unroll
        for (int d = 1; d < 64; d <<= 1) s += __shfl_xor(s, d);
        float inv = 0.8f / s;
        hp0 = act ? fmaf(e0, inv, 0.001f) : 0.f;
        hp1 = act ? fmaf(e1, inv, 0.001f) : 0.f;
        hp2 = act ? fmaf(e2, inv, 0.001f) : 0.f;
        hp3 = act ? fmaf(e3, inv, 0.001f) : 0.f;
    }
    float hc0 = hp0, hc1 = hc0 + hp1, hc2 = hc1 + hp2, hc3 = hc2 + hp3;
    float hrun = hc3, hts = hrun;
#pragma unroll
    for (int d = 1; d < 64; d <<= 1) { float u = __shfl_up(hts, d); if (lane >= d) hts += u; }
    float hexcl = hts - hrun;
    float ch0 = fmaf(sa, hexcl, sb);
    float ch1 = fmaf(sa, hexcl + hc0, sb);
    float ch2 = fmaf(sa, hexcl + hc1, sb);
    float ch3 = fmaf(sa, hexcl + hc2, sb);

    // ---- D (softplus): dd[4l..4l+3] = {dprev, dv0, dv1, dv2} ----
    float dv0, dv1, dv2, dv3;
    {
        float x0 = 0.f, x1 = 0.f, x2v = 0.f, x3 = 0.f;
        if (act) {
            bf16x4 v = *(const bf16x4*)&spr[400 + 4 * lane];
            x0 = (float)v[0]; x1 = (float)v[1]; x2v = (float)v[2]; x3 = (float)v[3];
        }
        auto spls = [](float x) {
            return fmaxf(x, 0.f) + __logf(1.f + __expf(-fabsf(x))) + 0.001f;
        };
        dv0 = spls(x0); dv1 = spls(x1); dv2 = spls(x2v); dv3 = spls(x3);
    }
    if (lane == 49) dv3 = EC;                     // dd[200] = EDGE
    float dprev = __shfl_up(dv3, 1);
    if (lane == 0) dprev = EC;                    // dd[0] = EDGE

    // ---- write param tables (aligned 16B stores) + tails ----
    if (act) {
        *(f32x4*)&cw[4 * lane] = (f32x4){cwl0, cwl1, cwl2, cwl3};
        *(f32x4*)&ch[4 * lane] = (f32x4){ch0, ch1, ch2, ch3};
        *(f32x4*)&dd[4 * lane] = (f32x4){dprev, dv0, dv1, dv2};
    }
    if (lane == 49) {
        cw[200] = 1.0f;                           // cw[:, -1].set(1.0)
        ch[200] = fmaf(sa, hts, sb);              // sa * total + sb
        dd[200] = EC;
    }

    // ---- scatter bin indices (tiny body; exact partition of [0,200)) ----
    if (act) {
        int b0 = rng(cwl0), b1 = rng(cwl1), b2 = rng(cwl2), b3 = rng(cwl3);
        int b4 = (lane == 49) ? 200 : rng(nexcl);
        for (int j = b0; j < b1; ++j) bx[j] = 4 * lane;
        for (int j = b1; j < b2; ++j) bx[j] = 4 * lane + 1;
        for (int j = b2; j < b3; ++j) bx[j] = 4 * lane + 2;
        for (int j = b3; j < b4; ++j) bx[j] = 4 * lane + 3;
    }
    asm volatile("s_waitcnt lgkmcnt(0)" ::: "memory");   // same-wave LDS RAW

    // ---- balanced gather: lane -> outputs j = lane + 50k ----
    if (act) {
        float* orow = out + (size_t)row * 200;
#pragma unroll
        for (int k = 0; k < 4; ++k) {
            int j = lane + 50 * k;
            int b = bx[j];
            float wl = cw[b], wr = cw[b + 1];
            float hl = ch[b], hr = ch[b + 1];
            float d0 = dd[b], d1 = dd[b + 1];
            float tau = ((float)j + 0.5f) * (1.f / 200.f);
            float w = wr - wl, h = hr - hl;
            float invw = 1.f / w;
            float delta = h * invw;
            float th = (tau - wl) * invw;
            float t1 = th * (1.f - th);
            float numer = h * fmaf(delta * th, th, d0 * t1);
            float denom = fmaf(d0 + d1 - 2.f * delta, t1, delta);
            orow[j] = hl + numer / denom;
        }
    }
}

// ---------------------------------------------------------------------------
// Host launcher
// ---------------------------------------------------------------------------
extern "C" void kernel_launch(void* const* d_in, const int* in_sizes, int n_in,
                              void* d_out, int out_size, void* d_ws, size_t ws_size,
                              hipStream_t stream)
{
    const float* inputs = (const float*)d_in[0];
    const float* W1  = (const float*)d_in[1];
    const float* b1  = (const float*)d_in[2];
    const float* g1  = (const float*)d_in[3];
    const float* be1 = (const float*)d_in[4];
    const float* W2  = (const float*)d_in[5];
    const float* b2  = (const float*)d_in[6];
    const float* g2  = (const float*)d_in[7];
    const float* be2 = (const float*)d_in[8];
    const float* WV  = (const float*)d_in[9];
    const float* bV  = (const float*)d_in[10];
    const float* Wa  = (const float*)d_in[11];
    const float* ba  = (const float*)d_in[12];
    const float* Wb  = (const float*)d_in[13];
    const float* bb  = (const float*)d_in[14];
    float* out = (float*)d_out;

    char* ws = (char*)d_ws;
    bf16*  w1b  = (bf16*) (ws + 0);          //   131072
    bf16*  w2b  = (bf16*) (ws + 131072);     //   524288
    bf16*  wcat = (bf16*) (ws + 655360);     //   655360 (640x512)
    float* bcat = (float*)(ws + 1310720);    //     2560 (640 f32)
    float* ab   = (float*)(ws + 1313280);    //   524288 (B x 2)
    bf16*  x    = (bf16*) (ws + 2097152);    // 67108864 (B x 512)
    bf16*  spb  = (bf16*) (ws + 69206016);   // 79691776 (B x 608)
    bf16*  xin  = (bf16*) (ws + 69206016);   // 16777216 (B x 128) — dead before G3 writes spb

    const int preptot = BATCH * 128 / 8 + 512 * 128 + 512 * 512 + NCAT * 512 + NCAT;
    prep_kernel<<<(preptot + 255) / 256, 256, 0, stream>>>(
        W1, W2, WV, bV, Wa, ba, Wb, bb, inputs, w1b, w2b, wcat, bcat, xin);

    gemm_ln<128><<<BATCH / 128, 1024, 0, stream>>>(xin, w1b, b1, g1, be1, x);
    gemm_ln<512><<<BATCH / 128, 1024, 0, stream>>>(x,   w2b, b2, g2, be2, x);
    gemm_cat<<<(BATCH / 128) * 2, 1024, 0, stream>>>(x, wcat, bcat, spb, ab);
    spline_kernel<<<BATCH / 4, 256, 0, stream>>>(spb, ab, out);
}